// Round 1
// baseline (251.437 us; speedup 1.0000x reference)
//
#include <hip/hip_runtime.h>
#include <hip/hip_bf16.h>

// x: [32, 2048, 17, 3] -> [65536, 51]
// h: [65536, 256], u: [65536, 768], y: [65536, 51]
static constexpr int M_ROWS = 32 * 2048;   // 65536
static constexpr int TC     = 64;          // scan chunk length
static constexpr int NCHUNK = 2048 / TC;   // 32

typedef __attribute__((ext_vector_type(8))) __bf16 bf16x8;
typedef __attribute__((ext_vector_type(4))) float  f32x4;

__device__ __forceinline__ void async_copy16(void* lds_ptr, const void* g_ptr) {
  __builtin_amdgcn_global_load_lds(
      (const __attribute__((address_space(1))) void*)g_ptr,
      (__attribute__((address_space(3))) void*)lds_ptr, 16, 0, 0);
}

__device__ __forceinline__ float sigmoid_f(float v) {
  return 1.f / (1.f + __expf(-v));
}
__device__ __forceinline__ float tanh_f(float v) {
  v = fminf(fmaxf(v, -15.f), 15.f);
  float e = __expf(-2.f * v);
  return (1.f - e) / (1.f + e);
}

// -------------------------------------------------------------------------
// Prep: W_l [2][256][768] f32 -> Wt [2][768][256] bf16 (transposed)
//       W_out [256][51] f32 -> WtO [128][256] bf16 (transposed, padded)
//       W_in [51][256] f32 -> WinT [256][64] bf16 (transposed, K-padded)
// -------------------------------------------------------------------------
__global__ __launch_bounds__(256) void prep_weights(
    const float* __restrict__ Wl, const float* __restrict__ Wout,
    const float* __restrict__ Win,
    __hip_bfloat16* __restrict__ Wt, __hip_bfloat16* __restrict__ WtO,
    __hip_bfloat16* __restrict__ WinT)
{
  const int idx = blockIdx.x * 256 + threadIdx.x;
  const int T1 = 2 * 768 * 256;          // 393216
  const int T2 = T1 + 128 * 256;         // 425984
  const int T3 = T2 + 256 * 64;          // 442368
  if (idx < T1) {
    int l = idx / (768 * 256);
    int rem = idx - l * 768 * 256;
    int n = rem >> 8;
    int k = rem & 255;
    Wt[idx] = __float2bfloat16(Wl[(size_t)l * 196608 + (size_t)k * 768 + n]);
  } else if (idx < T2) {
    int i2 = idx - T1;
    int n = i2 >> 8, k = i2 & 255;
    float v = (n < 51) ? Wout[(size_t)k * 51 + n] : 0.f;
    WtO[i2] = __float2bfloat16(v);
  } else if (idx < T3) {
    int i3 = idx - T2;
    int n = i3 >> 6, k = i3 & 63;
    float v = (k < 51) ? Win[(size_t)k * 256 + n] : 0.f;
    WinT[i3] = __float2bfloat16(v);
  }
}

// -------------------------------------------------------------------------
// cast/pad x [65536][51] f32 -> xb [65536][64] bf16
// -------------------------------------------------------------------------
__global__ __launch_bounds__(256) void cast_x(
    const float* __restrict__ x, __hip_bfloat16* __restrict__ xb)
{
  const int t = blockIdx.x * 256 + threadIdx.x;  // 524288 = 65536 * 8
  const int row = t >> 3, cg = t & 7;
  __hip_bfloat16 tmp[8];
#pragma unroll
  for (int i = 0; i < 8; ++i) {
    int c = cg * 8 + i;
    float v = (c < 51) ? x[(size_t)row * 51 + c] : 0.f;
    tmp[i] = __float2bfloat16(v);
  }
  *reinterpret_cast<int4*>(&xb[(size_t)row * 64 + cg * 8]) =
      *reinterpret_cast<const int4*>(tmp);
}

// -------------------------------------------------------------------------
// MFMA GEMM, 128x128 tile, 4 waves (2x2), 16x16x32 bf16, K templated.
// A: [M][K] bf16 row-major.  Bt: [N][K] bf16 (pre-transposed weights).
// LDS: double-buffered; per buf A[128][32] + B[128][32], bank-swizzled:
//   within each 64B row, 16B unit u holds col-block cb = (u - (row>>1)) & 3.
//   Staged by permuting the per-lane GLOBAL source col (linear LDS dest),
//   read back with the same permutation (rule 21: both-sides-or-neither).
// Epilogue: LDS-bounce (half-tile at a time, reusing staging LDS) so global
//   stores are 16B fully-coalesced instead of 64 scalar 2B stores/thread.
// MODE 0: out = u bf16 [M][768], +bias, sigmoid on cols >= 256.
// MODE 1: out = y f32 [M][51], +bias, only cols < 51 stored.
// MODE 2: out = h bf16 [M][256], +bias.
// -------------------------------------------------------------------------
template <int K, int MODE>
__global__ __launch_bounds__(256) void gemm_mfma(
    const __hip_bfloat16* __restrict__ A, const __hip_bfloat16* __restrict__ Bt,
    const float* __restrict__ bias, void* __restrict__ out)
{
  __shared__ __hip_bfloat16 lds[16384];  // 32 KB: 2 bufs x (A 4096 el + B 4096 el)
  constexpr int NT = K / 32;
  const int tid  = threadIdx.x;
  const int lane = tid & 63;
  const int wave = tid >> 6;
  const int wm = wave >> 1, wn = wave & 1;
  const int m0 = blockIdx.x * 128;
  const int n0 = blockIdx.y * 128;

  // staging: lane -> (row = lane>>2, swizzled source col-block)
  const int srow = lane >> 2;
  const int scb  = ((lane & 3) - ((lane >> 3) & 3)) & 3;
  const int c0   = wave * 2;  // this wave stages 16-row chunks c0, c0+1 of A and B

  const __hip_bfloat16* gA = A + (size_t)(m0 + c0 * 16 + srow) * K + scb * 8;
  const __hip_bfloat16* gB = Bt + (size_t)(n0 + c0 * 16 + srow) * K + scb * 8;

  f32x4 acc[4][4] = {};

  const int rsel = lane & 15;
  const int cls  = ((lane >> 4) + ((lane >> 1) & 3)) & 3;  // read-side swizzle class

  auto stage = [&](int kt, int buf) {
    char* la = (char*)lds + buf * 16384 + c0 * 1024;
    const __hip_bfloat16* a = gA + kt * 32;
    async_copy16(la, a);
    async_copy16(la + 1024, a + 16 * K);
    char* lb = (char*)lds + buf * 16384 + 8192 + c0 * 1024;
    const __hip_bfloat16* b = gB + kt * 32;
    async_copy16(lb, b);
    async_copy16(lb + 1024, b + 16 * K);
  };

  stage(0, 0);
  __syncthreads();
  int buf = 0;
  for (int kt = 0; kt < NT; ++kt) {
    if (kt + 1 < NT) stage(kt + 1, buf ^ 1);
    const __hip_bfloat16* base = lds + buf * 8192;
    bf16x8 af[4], bg[4];
#pragma unroll
    for (int i = 0; i < 4; ++i) {
      af[i] = *reinterpret_cast<const bf16x8*>(
          base + (wm * 64 + i * 16 + rsel) * 32 + cls * 8);
      bg[i] = *reinterpret_cast<const bf16x8*>(
          base + 4096 + (wn * 64 + i * 16 + rsel) * 32 + cls * 8);
    }
#pragma unroll
    for (int i = 0; i < 4; ++i)
#pragma unroll
      for (int j = 0; j < 4; ++j)
        acc[i][j] = __builtin_amdgcn_mfma_f32_16x16x32_bf16(af[i], bg[j],
                                                            acc[i][j], 0, 0, 0);
    if (kt + 1 < NT) { __syncthreads(); buf ^= 1; }
  }

  // ---- Epilogue via LDS bounce.  C/D layout: col = lane&15, row =
  // (lane>>4)*4 + e  [verified m89].  wm==half owns local rows [0,64).
  __syncthreads();  // staging-LDS reads finished; safe to reuse as bounce buf

  if (MODE == 1) {
    float* bt = (float*)lds;  // [64][72] f32, 18432 B
    for (int half = 0; half < 2; ++half) {
      if (wm == half && wn == 0) {
#pragma unroll
        for (int i = 0; i < 4; ++i)
#pragma unroll
          for (int j = 0; j < 4; ++j)
#pragma unroll
            for (int e = 0; e < 4; ++e) {
              int r = i * 16 + (lane >> 4) * 4 + e;   // 0..63
              int c = j * 16 + (lane & 15);           // 0..63
              if (c < 51) bt[r * 72 + c] = acc[i][j][e] + bias[c];
            }
      }
      __syncthreads();
      // 64 rows x 51 f32 is a contiguous 13056 B region of y: flat copy.
      float* yg = (float*)out + (size_t)(m0 + half * 64) * 51;
      for (int idx = tid; idx < 64 * 51; idx += 256) {
        int r = idx / 51, c = idx - r * 51;
        yg[idx] = bt[r * 72 + c];
      }
      __syncthreads();
    }
  } else {
    constexpr int W = (MODE == 0) ? 768 : 256;
    __hip_bfloat16* bt = (__hip_bfloat16*)lds;  // [64][136] bf16, 17408 B
    for (int half = 0; half < 2; ++half) {
      if (wm == half) {
#pragma unroll
        for (int i = 0; i < 4; ++i)
#pragma unroll
          for (int j = 0; j < 4; ++j)
#pragma unroll
            for (int e = 0; e < 4; ++e) {
              int r = i * 16 + (lane >> 4) * 4 + e;    // 0..63
              int c = wn * 64 + j * 16 + (lane & 15);  // 0..127
              float v = acc[i][j][e] + bias[n0 + c];
              if (MODE == 0 && n0 + c >= 256) v = sigmoid_f(v);
              bt[r * 136 + c] = __float2bfloat16(v);
            }
      }
      __syncthreads();
      // copy out 64 rows x 128 cols bf16: 256B contiguous per 16-lane group
#pragma unroll
      for (int it = 0; it < 4; ++it) {
        int r  = it * 16 + (tid >> 4);
        int uc = tid & 15;
        bf16x8 v = *reinterpret_cast<const bf16x8*>(&bt[r * 136 + uc * 8]);
        *reinterpret_cast<bf16x8*>(
            &((__hip_bfloat16*)out)[(size_t)(m0 + half * 64 + r) * W + n0 +
                                    uc * 8]) = v;
      }
      __syncthreads();
    }
  }
}

// -------------------------------------------------------------------------
// Chunked linear-recurrence scan.  u[m][0:256]=x_tilde, [256:512]=f, [512:768]=r
// -------------------------------------------------------------------------
__global__ __launch_bounds__(256) void scan_p1(
    const __hip_bfloat16* __restrict__ u, float* __restrict__ Pa,
    float* __restrict__ Pb)
{
  const int blk = blockIdx.x;
  const int b = blk >> 5, ch = blk & 31;
  const int h = threadIdx.x;
  const __hip_bfloat16* base = u + (size_t)(b * 2048 + ch * TC) * 768;
  float c = 0.f, a = 1.f;
#pragma unroll 4
  for (int t = 0; t < TC; ++t) {
    float f  = __bfloat162float(base[t * 768 + 256 + h]);
    float xt = __bfloat162float(base[t * 768 + h]);
    c = f * c + (1.f - f) * xt;
    a *= f;
  }
  const int o = (b * NCHUNK + ch) * 256 + h;
  Pa[o] = a;
  Pb[o] = c;
}

__global__ __launch_bounds__(256) void scan_p2(
    const float* __restrict__ Pa, const float* __restrict__ Pb,
    float* __restrict__ Cin)
{
  const int idx = blockIdx.x * 256 + threadIdx.x;  // 8192 = 32 b * 256 h
  const int b = idx >> 8, h = idx & 255;
  float c = 0.f;
  for (int ch = 0; ch < NCHUNK; ++ch) {
    const int o = (b * NCHUNK + ch) * 256 + h;
    Cin[o] = c;
    c = Pa[o] * c + Pb[o];
  }
}

__global__ __launch_bounds__(256) void scan_p3(
    const __hip_bfloat16* __restrict__ u, const float* __restrict__ Cin,
    __hip_bfloat16* __restrict__ hout)
{
  const int blk = blockIdx.x;
  const int b = blk >> 5, ch = blk & 31;
  const int h = threadIdx.x;
  const __hip_bfloat16* base = u + (size_t)(b * 2048 + ch * TC) * 768;
  __hip_bfloat16* ob = hout + (size_t)(b * 2048 + ch * TC) * 256;
  float c = Cin[(b * NCHUNK + ch) * 256 + h];
#pragma unroll 2
  for (int t = 0; t < TC; ++t) {
    float xt = __bfloat162float(base[t * 768 + h]);
    float f  = __bfloat162float(base[t * 768 + 256 + h]);
    float r  = __bfloat162float(base[t * 768 + 512 + h]);
    c = f * c + (1.f - f) * xt;
    float th = tanh_f(c);
    ob[t * 256 + h] = __float2bfloat16(r * th + (1.f - r) * xt);
  }
}

// -------------------------------------------------------------------------
extern "C" void kernel_launch(void* const* d_in, const int* in_sizes, int n_in,
                              void* d_out, int out_size, void* d_ws, size_t ws_size,
                              hipStream_t stream) {
  const float* x     = (const float*)d_in[0];
  const float* W_in  = (const float*)d_in[1];
  const float* b_in  = (const float*)d_in[2];
  const float* W_l   = (const float*)d_in[3];
  const float* b_l   = (const float*)d_in[4];
  const float* W_out = (const float*)d_in[5];
  const float* b_out = (const float*)d_in[6];

  char* ws = (char*)d_ws;
  const size_t U_B    = (size_t)M_ROWS * 768 * 2;      // 100,663,296
  const size_t H_B    = (size_t)M_ROWS * 256 * 2;      //  33,554,432
  const size_t WT_B   = (size_t)2 * 768 * 256 * 2;     //     786,432
  const size_t WTO_B  = (size_t)128 * 256 * 2;         //      65,536
  const size_t WIN_B  = (size_t)256 * 64 * 2;          //      32,768
  const size_t XB_B   = (size_t)M_ROWS * 64 * 2;       //   8,388,608
  const size_t AB_B   = (size_t)32 * NCHUNK * 256 * 4; //   1,048,576

  size_t off = 0;
  __hip_bfloat16* u    = (__hip_bfloat16*)(ws + off); off += U_B;
  __hip_bfloat16* hA   = (__hip_bfloat16*)(ws + off); off += H_B;
  __hip_bfloat16* hB   = (__hip_bfloat16*)(ws + off); off += H_B;
  __hip_bfloat16* Wt   = (__hip_bfloat16*)(ws + off); off += WT_B;
  __hip_bfloat16* WtO  = (__hip_bfloat16*)(ws + off); off += WTO_B;
  __hip_bfloat16* WinT = (__hip_bfloat16*)(ws + off); off += WIN_B;
  __hip_bfloat16* xb   = (__hip_bfloat16*)(ws + off); off += XB_B;
  float* Pa  = (float*)(ws + off); off += AB_B;
  float* Pb  = (float*)(ws + off); off += AB_B;
  float* Cin = (float*)(ws + off); off += AB_B;

  prep_weights<<<1728, 256, 0, stream>>>(W_l, W_out, W_in, Wt, WtO, WinT);
  cast_x<<<M_ROWS * 8 / 256, 256, 0, stream>>>(x, xb);

  // input GEMM: h0 = xb @ W_in^T + b_in   (K=64)
  gemm_mfma<64, 2><<<dim3(M_ROWS / 128, 2), 256, 0, stream>>>(xb, WinT, b_in, hA);

  // layer 0
  gemm_mfma<256, 0><<<dim3(M_ROWS / 128, 6), 256, 0, stream>>>(hA, Wt, b_l, u);
  scan_p1<<<32 * NCHUNK, 256, 0, stream>>>(u, Pa, Pb);
  scan_p2<<<32, 256, 0, stream>>>(Pa, Pb, Cin);
  scan_p3<<<32 * NCHUNK, 256, 0, stream>>>(u, Cin, hB);

  // layer 1
  gemm_mfma<256, 0><<<dim3(M_ROWS / 128, 6), 256, 0, stream>>>(hB, Wt + 768 * 256,
                                                               b_l + 768, u);
  scan_p1<<<32 * NCHUNK, 256, 0, stream>>>(u, Pa, Pb);
  scan_p2<<<32, 256, 0, stream>>>(Pa, Pb, Cin);
  scan_p3<<<32 * NCHUNK, 256, 0, stream>>>(u, Cin, hA);

  // output GEMM
  gemm_mfma<256, 1><<<dim3(M_ROWS / 128, 1), 256, 0, stream>>>(hA, WtO, b_out, d_out);

  (void)in_sizes; (void)n_in; (void)out_size; (void)ws_size;
}

// Round 2
// 238.024 us; speedup vs baseline: 1.0564x; 1.0564x over previous
//
#include <hip/hip_runtime.h>
#include <hip/hip_bf16.h>

// x: [32, 2048, 17, 3] -> [65536, 51]
// h: [65536, 256], u: [65536, 768], y: [65536, 51]
static constexpr int M_ROWS = 32 * 2048;   // 65536
static constexpr int TC     = 64;          // scan chunk length
static constexpr int NCHUNK = 2048 / TC;   // 32

typedef __attribute__((ext_vector_type(8))) __bf16 bf16x8;
typedef __attribute__((ext_vector_type(4))) float  f32x4;

#define VM_WAIT(N) asm volatile("s_waitcnt vmcnt(" #N ")" ::: "memory")
#define LGKM_WAIT0 asm volatile("s_waitcnt lgkmcnt(0)" ::: "memory")

__device__ __forceinline__ void async_copy16(void* lds_ptr, const void* g_ptr) {
  __builtin_amdgcn_global_load_lds(
      (const __attribute__((address_space(1))) void*)g_ptr,
      (__attribute__((address_space(3))) void*)lds_ptr, 16, 0, 0);
}

__device__ __forceinline__ float sigmoid_f(float v) {
  return 1.f / (1.f + __expf(-v));
}
__device__ __forceinline__ float tanh_f(float v) {
  v = fminf(fmaxf(v, -15.f), 15.f);
  float e = __expf(-2.f * v);
  return (1.f - e) / (1.f + e);
}

// -------------------------------------------------------------------------
// Prep: W_l [2][256][768] f32 -> Wt [2][768][256] bf16 (transposed)
//       W_out [256][51] f32 -> WtO [128][256] bf16 (transposed, padded)
//       W_in [51][256] f32 -> WinT [256][64] bf16 (transposed, K-padded)
// -------------------------------------------------------------------------
__global__ __launch_bounds__(256) void prep_weights(
    const float* __restrict__ Wl, const float* __restrict__ Wout,
    const float* __restrict__ Win,
    __hip_bfloat16* __restrict__ Wt, __hip_bfloat16* __restrict__ WtO,
    __hip_bfloat16* __restrict__ WinT)
{
  const int idx = blockIdx.x * 256 + threadIdx.x;
  const int T1 = 2 * 768 * 256;          // 393216
  const int T2 = T1 + 128 * 256;         // 425984
  const int T3 = T2 + 256 * 64;          // 442368
  if (idx < T1) {
    int l = idx / (768 * 256);
    int rem = idx - l * 768 * 256;
    int n = rem >> 8;
    int k = rem & 255;
    Wt[idx] = __float2bfloat16(Wl[(size_t)l * 196608 + (size_t)k * 768 + n]);
  } else if (idx < T2) {
    int i2 = idx - T1;
    int n = i2 >> 8, k = i2 & 255;
    float v = (n < 51) ? Wout[(size_t)k * 51 + n] : 0.f;
    WtO[i2] = __float2bfloat16(v);
  } else if (idx < T3) {
    int i3 = idx - T2;
    int n = i3 >> 6, k = i3 & 63;
    float v = (k < 51) ? Win[(size_t)k * 256 + n] : 0.f;
    WinT[i3] = __float2bfloat16(v);
  }
}

// -------------------------------------------------------------------------
// cast/pad x [65536][51] f32 -> xb [65536][64] bf16
// -------------------------------------------------------------------------
__global__ __launch_bounds__(256) void cast_x(
    const float* __restrict__ x, __hip_bfloat16* __restrict__ xb)
{
  const int t = blockIdx.x * 256 + threadIdx.x;  // 524288 = 65536 * 8
  const int row = t >> 3, cg = t & 7;
  __hip_bfloat16 tmp[8];
#pragma unroll
  for (int i = 0; i < 8; ++i) {
    int c = cg * 8 + i;
    float v = (c < 51) ? x[(size_t)row * 51 + c] : 0.f;
    tmp[i] = __float2bfloat16(v);
  }
  *reinterpret_cast<int4*>(&xb[(size_t)row * 64 + cg * 8]) =
      *reinterpret_cast<const int4*>(tmp);
}

// -------------------------------------------------------------------------
// MFMA GEMM, 128x128 tile, 4 waves (2x2), 16x16x32 bf16, K templated.
// A: [M][K] bf16 row-major.  Bt: [N][K] bf16 (pre-transposed weights).
//
// Structure (T3+T4 counted-vmcnt pipeline, raw barriers — never drain
// vmcnt to 0 in the loop):
//   - B panel [128][K] resident in LDS, loaded ONCE per block.  16B units
//     XOR-swizzled (u' = u ^ (row&7)) so stride-2K-byte row reads are
//     bank-conflict-free; staged by pre-swizzling the per-lane GLOBAL
//     source col (linear LDS dest, rule 21).
//   - A tiles [128][32] double-buffered, depth-2 prefetch.  Per K-step:
//       vmcnt(2); s_barrier;            // my+everyone's tile kt landed
//       ds_read A-frags + B-frags;
//       lgkmcnt(0); s_barrier;          // all waves done reading buf
//       stage(kt+2) into same buf;      // loads stay in flight across bars
//       setprio(1); 16x MFMA; setprio(0);
//   - A swizzle identical to round-0 (measured 0 bank conflicts).
// MODE 0: out = u bf16 [M][768], +bias, sigmoid on cols >= 256.
// MODE 1: out = y f32 [M][51], +bias, only cols < 51 stored.
// MODE 2: out = h bf16 [M][256], +bias.
// -------------------------------------------------------------------------
template <int K, int MODE>
__global__ __launch_bounds__(256) void gemm_mfma(
    const __hip_bfloat16* __restrict__ A, const __hip_bfloat16* __restrict__ Bt,
    const float* __restrict__ bias, void* __restrict__ out)
{
  constexpr int NT  = K / 32;   // K-steps
  constexpr int UPR = K / 8;    // 16B units per B row
  constexpr int RPC = 64 / UPR; // B rows per 1KB copy
  constexpr int NCB = K / 16;   // B copies per wave
  // B: 128*K el, A dbuf: 2 * 4096 el.  K=256: 80KB -> 2 blocks/CU.
  __shared__ __hip_bfloat16 lds[128 * K + 8192];

  const int tid  = threadIdx.x;
  const int lane = tid & 63;
  const int wave = tid >> 6;
  const int wm = wave >> 1, wn = wave & 1;
  const int m0 = blockIdx.x * 128;
  const int n0 = blockIdx.y * 128;

  // ---- B panel load (once).  LDS (row, u') holds global (row, u'^(row&7)).
  {
    const int lr = lane / UPR;   // row within 1KB copy
    const int ud = lane % UPR;   // dest 16B unit
#pragma unroll
    for (int ci = 0; ci < NCB; ++ci) {
      const int row = wave * 32 + ci * RPC + lr;  // local row 0..127
      const __hip_bfloat16* src =
          Bt + (size_t)(n0 + row) * K + (ud ^ (row & 7)) * 8;
      async_copy16((char*)lds + (wave * NCB + ci) * 1024, src);
    }
  }

  // ---- A staging (round-0 swizzle scheme, measured conflict-free)
  const int srow = lane >> 2;
  const int scb  = ((lane & 3) - ((lane >> 3) & 3)) & 3;
  const int c0   = wave * 2;  // this wave stages 16-row chunks c0, c0+1
  const __hip_bfloat16* gA = A + (size_t)(m0 + c0 * 16 + srow) * K + scb * 8;

  auto stageA = [&](int kt, int buf) {
    char* la = (char*)lds + (size_t)256 * K + buf * 8192 + c0 * 1024;
    const __hip_bfloat16* a = gA + kt * 32;
    async_copy16(la, a);
    async_copy16(la + 1024, a + 16 * K);
  };

  stageA(0, 0);
  stageA(1, 1);

  f32x4 acc[4][4] = {};
  const int rsel = lane & 15;
  const int clsA = ((lane >> 4) + ((lane >> 1) & 3)) & 3;  // A read swizzle
  const int clsB = lane >> 4;                              // B 16B unit in 64B

#pragma unroll
  for (int kt = 0; kt < NT; ++kt) {
    // tile kt (and, at kt=0, the whole B panel) landed; newest 2 may fly
    if (kt < NT - 1) { VM_WAIT(2); } else { VM_WAIT(0); }
    __builtin_amdgcn_s_barrier();

    bf16x8 af[4], bg[4];
    const __hip_bfloat16* aBase = lds + 128 * K + (kt & 1) * 4096;
#pragma unroll
    for (int i = 0; i < 4; ++i)
      af[i] = *reinterpret_cast<const bf16x8*>(
          aBase + (wm * 64 + i * 16 + rsel) * 32 + clsA * 8);
#pragma unroll
    for (int j = 0; j < 4; ++j) {
      const int brow = wn * 64 + j * 16 + rsel;
      const int up = (kt * 4 + clsB) ^ (brow & 7);
      bg[j] = *reinterpret_cast<const bf16x8*>(lds + (size_t)brow * K + up * 8);
    }
    LGKM_WAIT0;                          // frags in regs
    __builtin_amdgcn_sched_barrier(0);   // rule 18
    __builtin_amdgcn_s_barrier();        // all waves done reading this buf

    if (kt + 2 < NT) stageA(kt + 2, kt & 1);  // overwrite just-read buf

    __builtin_amdgcn_s_setprio(1);
#pragma unroll
    for (int i = 0; i < 4; ++i)
#pragma unroll
      for (int j = 0; j < 4; ++j)
        acc[i][j] = __builtin_amdgcn_mfma_f32_16x16x32_bf16(af[i], bg[j],
                                                            acc[i][j], 0, 0, 0);
    __builtin_amdgcn_s_setprio(0);
  }

  // Epilogue.  C/D layout: col = lane&15, row = (lane>>4)*4 + e  [m89]
  const int rbase = m0 + wm * 64 + (lane >> 4) * 4;
  const int cbase = n0 + wn * 64 + (lane & 15);
#pragma unroll
  for (int i = 0; i < 4; ++i) {
#pragma unroll
    for (int j = 0; j < 4; ++j) {
#pragma unroll
      for (int e = 0; e < 4; ++e) {
        const int row = rbase + i * 16 + e;
        const int col = cbase + j * 16;
        float v = acc[i][j][e];
        if (MODE == 0) {
          v += bias[col];
          if (col >= 256) v = sigmoid_f(v);
          ((__hip_bfloat16*)out)[(size_t)row * 768 + col] = __float2bfloat16(v);
        } else if (MODE == 1) {
          if (col < 51) {
            v += bias[col];
            ((float*)out)[(size_t)row * 51 + col] = v;
          }
        } else {
          v += bias[col];
          ((__hip_bfloat16*)out)[(size_t)row * 256 + col] = __float2bfloat16(v);
        }
      }
    }
  }
}

// -------------------------------------------------------------------------
// Chunked linear-recurrence scan.  u[m][0:256]=x_tilde, [256:512]=f, [512:768]=r
// -------------------------------------------------------------------------
__global__ __launch_bounds__(256) void scan_p1(
    const __hip_bfloat16* __restrict__ u, float* __restrict__ Pa,
    float* __restrict__ Pb)
{
  const int blk = blockIdx.x;
  const int b = blk >> 5, ch = blk & 31;
  const int h = threadIdx.x;
  const __hip_bfloat16* base = u + (size_t)(b * 2048 + ch * TC) * 768;
  float c = 0.f, a = 1.f;
#pragma unroll 4
  for (int t = 0; t < TC; ++t) {
    float f  = __bfloat162float(base[t * 768 + 256 + h]);
    float xt = __bfloat162float(base[t * 768 + h]);
    c = f * c + (1.f - f) * xt;
    a *= f;
  }
  const int o = (b * NCHUNK + ch) * 256 + h;
  Pa[o] = a;
  Pb[o] = c;
}

__global__ __launch_bounds__(256) void scan_p2(
    const float* __restrict__ Pa, const float* __restrict__ Pb,
    float* __restrict__ Cin)
{
  const int idx = blockIdx.x * 256 + threadIdx.x;  // 8192 = 32 b * 256 h
  const int b = idx >> 8, h = idx & 255;
  float c = 0.f;
  for (int ch = 0; ch < NCHUNK; ++ch) {
    const int o = (b * NCHUNK + ch) * 256 + h;
    Cin[o] = c;
    c = Pa[o] * c + Pb[o];
  }
}

__global__ __launch_bounds__(256) void scan_p3(
    const __hip_bfloat16* __restrict__ u, const float* __restrict__ Cin,
    __hip_bfloat16* __restrict__ hout)
{
  const int blk = blockIdx.x;
  const int b = blk >> 5, ch = blk & 31;
  const int h = threadIdx.x;
  const __hip_bfloat16* base = u + (size_t)(b * 2048 + ch * TC) * 768;
  __hip_bfloat16* ob = hout + (size_t)(b * 2048 + ch * TC) * 256;
  float c = Cin[(b * NCHUNK + ch) * 256 + h];
#pragma unroll 2
  for (int t = 0; t < TC; ++t) {
    float xt = __bfloat162float(base[t * 768 + h]);
    float f  = __bfloat162float(base[t * 768 + 256 + h]);
    float r  = __bfloat162float(base[t * 768 + 512 + h]);
    c = f * c + (1.f - f) * xt;
    float th = tanh_f(c);
    ob[t * 256 + h] = __float2bfloat16(r * th + (1.f - r) * xt);
  }
}

// -------------------------------------------------------------------------
extern "C" void kernel_launch(void* const* d_in, const int* in_sizes, int n_in,
                              void* d_out, int out_size, void* d_ws, size_t ws_size,
                              hipStream_t stream) {
  const float* x     = (const float*)d_in[0];
  const float* W_in  = (const float*)d_in[1];
  const float* b_in  = (const float*)d_in[2];
  const float* W_l   = (const float*)d_in[3];
  const float* b_l   = (const float*)d_in[4];
  const float* W_out = (const float*)d_in[5];
  const float* b_out = (const float*)d_in[6];

  char* ws = (char*)d_ws;
  const size_t U_B    = (size_t)M_ROWS * 768 * 2;      // 100,663,296
  const size_t H_B    = (size_t)M_ROWS * 256 * 2;      //  33,554,432
  const size_t WT_B   = (size_t)2 * 768 * 256 * 2;     //     786,432
  const size_t WTO_B  = (size_t)128 * 256 * 2;         //      65,536
  const size_t WIN_B  = (size_t)256 * 64 * 2;          //      32,768
  const size_t XB_B   = (size_t)M_ROWS * 64 * 2;       //   8,388,608
  const size_t AB_B   = (size_t)32 * NCHUNK * 256 * 4; //   1,048,576

  size_t off = 0;
  __hip_bfloat16* u    = (__hip_bfloat16*)(ws + off); off += U_B;
  __hip_bfloat16* hA   = (__hip_bfloat16*)(ws + off); off += H_B;
  __hip_bfloat16* hB   = (__hip_bfloat16*)(ws + off); off += H_B;
  __hip_bfloat16* Wt   = (__hip_bfloat16*)(ws + off); off += WT_B;
  __hip_bfloat16* WtO  = (__hip_bfloat16*)(ws + off); off += WTO_B;
  __hip_bfloat16* WinT = (__hip_bfloat16*)(ws + off); off += WIN_B;
  __hip_bfloat16* xb   = (__hip_bfloat16*)(ws + off); off += XB_B;
  float* Pa  = (float*)(ws + off); off += AB_B;
  float* Pb  = (float*)(ws + off); off += AB_B;
  float* Cin = (float*)(ws + off); off += AB_B;

  prep_weights<<<1728, 256, 0, stream>>>(W_l, W_out, W_in, Wt, WtO, WinT);
  cast_x<<<M_ROWS * 8 / 256, 256, 0, stream>>>(x, xb);

  // input GEMM: h0 = xb @ W_in^T + b_in   (K=64)
  gemm_mfma<64, 2><<<dim3(M_ROWS / 128, 2), 256, 0, stream>>>(xb, WinT, b_in, hA);

  // layer 0
  gemm_mfma<256, 0><<<dim3(M_ROWS / 128, 6), 256, 0, stream>>>(hA, Wt, b_l, u);
  scan_p1<<<32 * NCHUNK, 256, 0, stream>>>(u, Pa, Pb);
  scan_p2<<<32, 256, 0, stream>>>(Pa, Pb, Cin);
  scan_p3<<<32 * NCHUNK, 256, 0, stream>>>(u, Cin, hB);

  // layer 1
  gemm_mfma<256, 0><<<dim3(M_ROWS / 128, 6), 256, 0, stream>>>(hB, Wt + 768 * 256,
                                                               b_l + 768, u);
  scan_p1<<<32 * NCHUNK, 256, 0, stream>>>(u, Pa, Pb);
  scan_p2<<<32, 256, 0, stream>>>(Pa, Pb, Cin);
  scan_p3<<<32 * NCHUNK, 256, 0, stream>>>(u, Cin, hA);

  // output GEMM
  gemm_mfma<256, 1><<<dim3(M_ROWS / 128, 1), 256, 0, stream>>>(hA, WtO, b_out, d_out);

  (void)in_sizes; (void)n_in; (void)out_size; (void)ws_size;
}

// Round 3
// 224.759 us; speedup vs baseline: 1.1187x; 1.0590x over previous
//
#include <hip/hip_runtime.h>
#include <hip/hip_bf16.h>

// x: [32, 2048, 17, 3] -> [65536, 51]
// h: [65536, 256], u: [65536, 768], y: [65536, 51]
static constexpr int M_ROWS = 32 * 2048;   // 65536
static constexpr int TC     = 64;          // scan chunk length
static constexpr int NCHUNK = 2048 / TC;   // 32

typedef __attribute__((ext_vector_type(8))) __bf16 bf16x8;
typedef __attribute__((ext_vector_type(4))) float  f32x4;

#define VM_WAIT(N) asm volatile("s_waitcnt vmcnt(" #N ")" ::: "memory")
#define LGKM_WAIT0 asm volatile("s_waitcnt lgkmcnt(0)" ::: "memory")

__device__ __forceinline__ void async_copy16(void* lds_ptr, const void* g_ptr) {
  __builtin_amdgcn_global_load_lds(
      (const __attribute__((address_space(1))) void*)g_ptr,
      (__attribute__((address_space(3))) void*)lds_ptr, 16, 0, 0);
}

__device__ __forceinline__ float sigmoid_f(float v) {
  return 1.f / (1.f + __expf(-v));
}
__device__ __forceinline__ float tanh_f(float v) {
  v = fminf(fmaxf(v, -15.f), 15.f);
  float e = __expf(-2.f * v);
  return (1.f - e) / (1.f + e);
}

// -------------------------------------------------------------------------
// Prep: W_l [2][256][768] f32 -> Wt [2][768][256] bf16 (transposed)
//       W_out [256][51] f32 -> WtO [128][256] bf16 (transposed, padded)
//       W_in [51][256] f32 -> WinT [256][64] bf16 (transposed, K-padded)
// -------------------------------------------------------------------------
__global__ __launch_bounds__(256) void prep_weights(
    const float* __restrict__ Wl, const float* __restrict__ Wout,
    const float* __restrict__ Win,
    __hip_bfloat16* __restrict__ Wt, __hip_bfloat16* __restrict__ WtO,
    __hip_bfloat16* __restrict__ WinT)
{
  const int idx = blockIdx.x * 256 + threadIdx.x;
  const int T1 = 2 * 768 * 256;          // 393216
  const int T2 = T1 + 128 * 256;         // 425984
  const int T3 = T2 + 256 * 64;          // 442368
  if (idx < T1) {
    int l = idx / (768 * 256);
    int rem = idx - l * 768 * 256;
    int n = rem >> 8;
    int k = rem & 255;
    Wt[idx] = __float2bfloat16(Wl[(size_t)l * 196608 + (size_t)k * 768 + n]);
  } else if (idx < T2) {
    int i2 = idx - T1;
    int n = i2 >> 8, k = i2 & 255;
    float v = (n < 51) ? Wout[(size_t)k * 51 + n] : 0.f;
    WtO[i2] = __float2bfloat16(v);
  } else if (idx < T3) {
    int i3 = idx - T2;
    int n = i3 >> 6, k = i3 & 63;
    float v = (k < 51) ? Win[(size_t)k * 256 + n] : 0.f;
    WinT[i3] = __float2bfloat16(v);
  }
}

// -------------------------------------------------------------------------
// cast/pad x [65536][51] f32 -> xb [65536][64] bf16
// -------------------------------------------------------------------------
__global__ __launch_bounds__(256) void cast_x(
    const float* __restrict__ x, __hip_bfloat16* __restrict__ xb)
{
  const int t = blockIdx.x * 256 + threadIdx.x;  // 524288 = 65536 * 8
  const int row = t >> 3, cg = t & 7;
  __hip_bfloat16 tmp[8];
#pragma unroll
  for (int i = 0; i < 8; ++i) {
    int c = cg * 8 + i;
    float v = (c < 51) ? x[(size_t)row * 51 + c] : 0.f;
    tmp[i] = __float2bfloat16(v);
  }
  *reinterpret_cast<int4*>(&xb[(size_t)row * 64 + cg * 8]) =
      *reinterpret_cast<const int4*>(tmp);
}

// -------------------------------------------------------------------------
// MFMA GEMM, 128x128 tile, 4 waves (2x2), 16x16x32 bf16, K templated.
// A: [M][K] bf16 row-major.  Bt: [N][K] bf16 (pre-transposed weights).
// LDS: TRIPLE-buffered (depth-2 prefetch); per buf A[128][32] + B[128][32],
//   bank-swizzled exactly as round-0 (measured 0 conflicts):
//   within each 64B row, 16B unit u holds col-block cb = (u - (row>>1)) & 3.
//   Staged by permuting the per-lane GLOBAL source col (linear LDS dest),
//   read back with the same permutation (rule 21).
// Sync structure (T3+T4): raw s_barrier + counted vmcnt — prefetch loads for
//   tiles kt+1, kt+2 stay in flight across barriers; never drain to 0 in
//   the loop.  Per K-step:
//     vmcnt(4); s_barrier;             // tile kt landed everywhere
//     ds_read frags from buf kt%3;
//     lgkmcnt(0); sched_barrier(0);    // frags in regs (rule 18)
//     s_barrier;                       // all waves done reading buf kt%3
//     stage(kt+2) -> buf (kt+2)%3;     // last read 2 iters ago: safe
//     setprio(1); 16x MFMA; setprio(0);
// MODE 0: out = u bf16 [M][768], +bias, sigmoid on cols >= 256.
// MODE 1: out = y f32 [M][51], +bias, only cols < 51 stored.
// MODE 2: out = h bf16 [M][256], +bias.
// -------------------------------------------------------------------------
template <int K, int MODE>
__global__ __launch_bounds__(256) void gemm_mfma(
    const __hip_bfloat16* __restrict__ A, const __hip_bfloat16* __restrict__ Bt,
    const float* __restrict__ bias, void* __restrict__ out)
{
  __shared__ __hip_bfloat16 lds[24576];  // 48 KB: 3 bufs x (A 4096 el + B 4096 el)
  constexpr int NT = K / 32;
  const int tid  = threadIdx.x;
  const int lane = tid & 63;
  const int wave = tid >> 6;
  const int wm = wave >> 1, wn = wave & 1;
  const int m0 = blockIdx.x * 128;
  const int n0 = blockIdx.y * 128;

  // staging: lane -> (row = lane>>2, swizzled source col-block)
  const int srow = lane >> 2;
  const int scb  = ((lane & 3) - ((lane >> 3) & 3)) & 3;
  const int c0   = wave * 2;  // this wave stages 16-row chunks c0, c0+1 of A and B

  const __hip_bfloat16* gA = A + (size_t)(m0 + c0 * 16 + srow) * K + scb * 8;
  const __hip_bfloat16* gB = Bt + (size_t)(n0 + c0 * 16 + srow) * K + scb * 8;

  f32x4 acc[4][4] = {};

  const int rsel = lane & 15;
  const int cls  = ((lane >> 4) + ((lane >> 1) & 3)) & 3;  // read-side swizzle class

  auto stage = [&](int kt, int buf) {
    char* la = (char*)lds + buf * 16384 + c0 * 1024;
    const __hip_bfloat16* a = gA + kt * 32;
    async_copy16(la, a);
    async_copy16(la + 1024, a + 16 * K);
    char* lb = (char*)lds + buf * 16384 + 8192 + c0 * 1024;
    const __hip_bfloat16* b = gB + kt * 32;
    async_copy16(lb, b);
    async_copy16(lb + 1024, b + 16 * K);
  };

  stage(0, 0);
  stage(1, 1);

#pragma unroll
  for (int kt = 0; kt < NT; ++kt) {
    // Outstanding here: tiles kt, kt+1 (8 loads).  Drain to tile kt landed.
    if (kt < NT - 1) { VM_WAIT(4); } else { VM_WAIT(0); }
    __builtin_amdgcn_s_barrier();

    const __hip_bfloat16* base = lds + (kt % 3) * 8192;
    bf16x8 af[4], bg[4];
#pragma unroll
    for (int i = 0; i < 4; ++i) {
      af[i] = *reinterpret_cast<const bf16x8*>(
          base + (wm * 64 + i * 16 + rsel) * 32 + cls * 8);
      bg[i] = *reinterpret_cast<const bf16x8*>(
          base + 4096 + (wn * 64 + i * 16 + rsel) * 32 + cls * 8);
    }
    LGKM_WAIT0;                          // frags in regs
    __builtin_amdgcn_sched_barrier(0);   // rule 18
    __builtin_amdgcn_s_barrier();        // all waves done reading buf kt%3

    if (kt + 2 < NT) stage(kt + 2, (kt + 2) % 3);

    __builtin_amdgcn_s_setprio(1);
#pragma unroll
    for (int i = 0; i < 4; ++i)
#pragma unroll
      for (int j = 0; j < 4; ++j)
        acc[i][j] = __builtin_amdgcn_mfma_f32_16x16x32_bf16(af[i], bg[j],
                                                            acc[i][j], 0, 0, 0);
    __builtin_amdgcn_s_setprio(0);
  }

  // Epilogue.  C/D layout: col = lane&15, row = (lane>>4)*4 + e  [verified m89]
  const int rbase = m0 + wm * 64 + (lane >> 4) * 4;
  const int cbase = n0 + wn * 64 + (lane & 15);
#pragma unroll
  for (int i = 0; i < 4; ++i) {
#pragma unroll
    for (int j = 0; j < 4; ++j) {
#pragma unroll
      for (int e = 0; e < 4; ++e) {
        const int row = rbase + i * 16 + e;
        const int col = cbase + j * 16;
        float v = acc[i][j][e];
        if (MODE == 0) {
          v += bias[col];
          if (col >= 256) v = sigmoid_f(v);
          ((__hip_bfloat16*)out)[(size_t)row * 768 + col] = __float2bfloat16(v);
        } else if (MODE == 1) {
          if (col < 51) {
            v += bias[col];
            ((float*)out)[(size_t)row * 51 + col] = v;
          }
        } else {
          v += bias[col];
          ((__hip_bfloat16*)out)[(size_t)row * 256 + col] = __float2bfloat16(v);
        }
      }
    }
  }
}

// -------------------------------------------------------------------------
// Chunked linear-recurrence scan.  u[m][0:256]=x_tilde, [256:512]=f, [512:768]=r
// -------------------------------------------------------------------------
__global__ __launch_bounds__(256) void scan_p1(
    const __hip_bfloat16* __restrict__ u, float* __restrict__ Pa,
    float* __restrict__ Pb)
{
  const int blk = blockIdx.x;
  const int b = blk >> 5, ch = blk & 31;
  const int h = threadIdx.x;
  const __hip_bfloat16* base = u + (size_t)(b * 2048 + ch * TC) * 768;
  float c = 0.f, a = 1.f;
#pragma unroll 4
  for (int t = 0; t < TC; ++t) {
    float f  = __bfloat162float(base[t * 768 + 256 + h]);
    float xt = __bfloat162float(base[t * 768 + h]);
    c = f * c + (1.f - f) * xt;
    a *= f;
  }
  const int o = (b * NCHUNK + ch) * 256 + h;
  Pa[o] = a;
  Pb[o] = c;
}

__global__ __launch_bounds__(256) void scan_p2(
    const float* __restrict__ Pa, const float* __restrict__ Pb,
    float* __restrict__ Cin)
{
  const int idx = blockIdx.x * 256 + threadIdx.x;  // 8192 = 32 b * 256 h
  const int b = idx >> 8, h = idx & 255;
  float c = 0.f;
  for (int ch = 0; ch < NCHUNK; ++ch) {
    const int o = (b * NCHUNK + ch) * 256 + h;
    Cin[o] = c;
    c = Pa[o] * c + Pb[o];
  }
}

__global__ __launch_bounds__(256) void scan_p3(
    const __hip_bfloat16* __restrict__ u, const float* __restrict__ Cin,
    __hip_bfloat16* __restrict__ hout)
{
  const int blk = blockIdx.x;
  const int b = blk >> 5, ch = blk & 31;
  const int h = threadIdx.x;
  const __hip_bfloat16* base = u + (size_t)(b * 2048 + ch * TC) * 768;
  __hip_bfloat16* ob = hout + (size_t)(b * 2048 + ch * TC) * 256;
  float c = Cin[(b * NCHUNK + ch) * 256 + h];
#pragma unroll 2
  for (int t = 0; t < TC; ++t) {
    float xt = __bfloat162float(base[t * 768 + h]);
    float f  = __bfloat162float(base[t * 768 + 256 + h]);
    float r  = __bfloat162float(base[t * 768 + 512 + h]);
    c = f * c + (1.f - f) * xt;
    float th = tanh_f(c);
    ob[t * 256 + h] = __float2bfloat16(r * th + (1.f - r) * xt);
  }
}

// -------------------------------------------------------------------------
extern "C" void kernel_launch(void* const* d_in, const int* in_sizes, int n_in,
                              void* d_out, int out_size, void* d_ws, size_t ws_size,
                              hipStream_t stream) {
  const float* x     = (const float*)d_in[0];
  const float* W_in  = (const float*)d_in[1];
  const float* b_in  = (const float*)d_in[2];
  const float* W_l   = (const float*)d_in[3];
  const float* b_l   = (const float*)d_in[4];
  const float* W_out = (const float*)d_in[5];
  const float* b_out = (const float*)d_in[6];

  char* ws = (char*)d_ws;
  const size_t U_B    = (size_t)M_ROWS * 768 * 2;      // 100,663,296
  const size_t H_B    = (size_t)M_ROWS * 256 * 2;      //  33,554,432
  const size_t WT_B   = (size_t)2 * 768 * 256 * 2;     //     786,432
  const size_t WTO_B  = (size_t)128 * 256 * 2;         //      65,536
  const size_t WIN_B  = (size_t)256 * 64 * 2;          //      32,768
  const size_t XB_B   = (size_t)M_ROWS * 64 * 2;       //   8,388,608
  const size_t AB_B   = (size_t)32 * NCHUNK * 256 * 4; //   1,048,576

  size_t off = 0;
  __hip_bfloat16* u    = (__hip_bfloat16*)(ws + off); off += U_B;
  __hip_bfloat16* hA   = (__hip_bfloat16*)(ws + off); off += H_B;
  __hip_bfloat16* hB   = (__hip_bfloat16*)(ws + off); off += H_B;
  __hip_bfloat16* Wt   = (__hip_bfloat16*)(ws + off); off += WT_B;
  __hip_bfloat16* WtO  = (__hip_bfloat16*)(ws + off); off += WTO_B;
  __hip_bfloat16* WinT = (__hip_bfloat16*)(ws + off); off += WIN_B;
  __hip_bfloat16* xb   = (__hip_bfloat16*)(ws + off); off += XB_B;
  float* Pa  = (float*)(ws + off); off += AB_B;
  float* Pb  = (float*)(ws + off); off += AB_B;
  float* Cin = (float*)(ws + off); off += AB_B;

  prep_weights<<<1728, 256, 0, stream>>>(W_l, W_out, W_in, Wt, WtO, WinT);
  cast_x<<<M_ROWS * 8 / 256, 256, 0, stream>>>(x, xb);

  // input GEMM: h0 = xb @ W_in^T + b_in   (K=64)
  gemm_mfma<64, 2><<<dim3(M_ROWS / 128, 2), 256, 0, stream>>>(xb, WinT, b_in, hA);

  // layer 0
  gemm_mfma<256, 0><<<dim3(M_ROWS / 128, 6), 256, 0, stream>>>(hA, Wt, b_l, u);
  scan_p1<<<32 * NCHUNK, 256, 0, stream>>>(u, Pa, Pb);
  scan_p2<<<32, 256, 0, stream>>>(Pa, Pb, Cin);
  scan_p3<<<32 * NCHUNK, 256, 0, stream>>>(u, Cin, hB);

  // layer 1
  gemm_mfma<256, 0><<<dim3(M_ROWS / 128, 6), 256, 0, stream>>>(hB, Wt + 768 * 256,
                                                               b_l + 768, u);
  scan_p1<<<32 * NCHUNK, 256, 0, stream>>>(u, Pa, Pb);
  scan_p2<<<32, 256, 0, stream>>>(Pa, Pb, Cin);
  scan_p3<<<32 * NCHUNK, 256, 0, stream>>>(u, Cin, hA);

  // output GEMM
  gemm_mfma<256, 1><<<dim3(M_ROWS / 128, 1), 256, 0, stream>>>(hA, WtO, b_out, d_out);

  (void)in_sizes; (void)n_in; (void)out_size; (void)ws_size;
}

// Round 4
// 208.416 us; speedup vs baseline: 1.2064x; 1.0784x over previous
//
#include <hip/hip_runtime.h>
#include <hip/hip_bf16.h>

// x: [32, 2048, 17, 3] -> [65536, 51]
// h: [65536, 256], u: [65536, 768], y: [65536, 51]
static constexpr int M_ROWS = 32 * 2048;   // 65536
static constexpr int TC     = 64;          // scan chunk length
static constexpr int NCHUNK = 2048 / TC;   // 32

typedef __attribute__((ext_vector_type(8))) __bf16 bf16x8;
typedef __attribute__((ext_vector_type(4))) float  f32x4;

#define VM_WAIT(N) asm volatile("s_waitcnt vmcnt(" #N ")" ::: "memory")
#define LGKM_WAIT0 asm volatile("s_waitcnt lgkmcnt(0)" ::: "memory")

__device__ __forceinline__ void async_copy16(void* lds_ptr, const void* g_ptr) {
  __builtin_amdgcn_global_load_lds(
      (const __attribute__((address_space(1))) void*)g_ptr,
      (__attribute__((address_space(3))) void*)lds_ptr, 16, 0, 0);
}

__device__ __forceinline__ float sigmoid_f(float v) {
  return 1.f / (1.f + __expf(-v));
}
__device__ __forceinline__ float tanh_f(float v) {
  v = fminf(fmaxf(v, -15.f), 15.f);
  float e = __expf(-2.f * v);
  return (1.f - e) / (1.f + e);
}

// -------------------------------------------------------------------------
// Prep: W_l [2][256][768] f32 -> Wt [2][768][256] bf16 (transposed)
//       W_out [256][51] f32 -> WtO [128][256] bf16 (transposed, padded)
//       W_in [51][256] f32 -> WinT [256][64] bf16 (transposed, K-padded)
// -------------------------------------------------------------------------
__global__ __launch_bounds__(256) void prep_weights(
    const float* __restrict__ Wl, const float* __restrict__ Wout,
    const float* __restrict__ Win,
    __hip_bfloat16* __restrict__ Wt, __hip_bfloat16* __restrict__ WtO,
    __hip_bfloat16* __restrict__ WinT)
{
  const int idx = blockIdx.x * 256 + threadIdx.x;
  const int T1 = 2 * 768 * 256;          // 393216
  const int T2 = T1 + 128 * 256;         // 425984
  const int T3 = T2 + 256 * 64;          // 442368
  if (idx < T1) {
    int l = idx / (768 * 256);
    int rem = idx - l * 768 * 256;
    int n = rem >> 8;
    int k = rem & 255;
    Wt[idx] = __float2bfloat16(Wl[(size_t)l * 196608 + (size_t)k * 768 + n]);
  } else if (idx < T2) {
    int i2 = idx - T1;
    int n = i2 >> 8, k = i2 & 255;
    float v = (n < 51) ? Wout[(size_t)k * 51 + n] : 0.f;
    WtO[i2] = __float2bfloat16(v);
  } else if (idx < T3) {
    int i3 = idx - T2;
    int n = i3 >> 6, k = i3 & 63;
    float v = (k < 51) ? Win[(size_t)k * 256 + n] : 0.f;
    WinT[i3] = __float2bfloat16(v);
  }
}

// -------------------------------------------------------------------------
// cast/pad x [65536][51] f32 -> xb [65536][64] bf16
// -------------------------------------------------------------------------
__global__ __launch_bounds__(256) void cast_x(
    const float* __restrict__ x, __hip_bfloat16* __restrict__ xb)
{
  const int t = blockIdx.x * 256 + threadIdx.x;  // 524288 = 65536 * 8
  const int row = t >> 3, cg = t & 7;
  __hip_bfloat16 tmp[8];
#pragma unroll
  for (int i = 0; i < 8; ++i) {
    int c = cg * 8 + i;
    float v = (c < 51) ? x[(size_t)row * 51 + c] : 0.f;
    tmp[i] = __float2bfloat16(v);
  }
  *reinterpret_cast<int4*>(&xb[(size_t)row * 64 + cg * 8]) =
      *reinterpret_cast<const int4*>(tmp);
}

// -------------------------------------------------------------------------
// MFMA GEMM, 128x128 tile, 4 waves (2x2), 16x16x32 bf16, K templated.
// A: [M][K] bf16 row-major.  Bt: [N][K] bf16 (pre-transposed weights).
//
// Grid: 1-D, XCD-chunked (T1): xcd = bid&7 owns m-tiles [xcd*64, xcd*64+64)
//   x all NBN n-tiles, n fastest.  The NBN blocks sharing an A-tile are
//   consecutive on ONE XCD -> A fetched from HBM once, re-read from L2.
//   Bijective: 512*NBN % 8 == 0 for all modes.
// LDS: TRIPLE-buffered (depth-2 prefetch); per buf A[128][32] + B[128][32],
//   bank-swizzled exactly as round-0 (measured 0 conflicts):
//   within each 64B row, 16B unit u holds col-block cb = (u - (row>>1)) & 3.
//   Staged by permuting the per-lane GLOBAL source col (linear LDS dest),
//   read back with the same permutation (rule 21).
// Sync structure (T3+T4): raw s_barrier + counted vmcnt — prefetch loads for
//   tiles kt+1, kt+2 stay in flight across barriers; never drain to 0 in
//   the loop.
// MODE 0: out = u bf16 [M][768], +bias, sigmoid on cols >= 256.  NBN=6.
// MODE 1: out = y f32 [M][51], +bias, only cols < 51 stored.      NBN=1.
// MODE 2: out = h bf16 [M][256], +bias.                           NBN=2.
// -------------------------------------------------------------------------
template <int K, int MODE>
__global__ __launch_bounds__(256) void gemm_mfma(
    const __hip_bfloat16* __restrict__ A, const __hip_bfloat16* __restrict__ Bt,
    const float* __restrict__ bias, void* __restrict__ out)
{
  __shared__ __hip_bfloat16 lds[24576];  // 48 KB: 3 bufs x (A 4096 el + B 4096 el)
  constexpr int NT  = K / 32;
  constexpr int NBN = (MODE == 0) ? 6 : (MODE == 2) ? 2 : 1;
  const int tid  = threadIdx.x;
  const int lane = tid & 63;
  const int wave = tid >> 6;
  const int wm = wave >> 1, wn = wave & 1;

  // XCD-chunked block swizzle (T1)
  const int bid  = blockIdx.x;
  const int xcd  = bid & 7;
  const int slot = bid >> 3;            // 64*NBN slots per XCD
  const int mg   = slot / NBN;
  const int nb   = slot - mg * NBN;
  const int m0   = (xcd * 64 + mg) * 128;
  const int n0   = nb * 128;

  // staging: lane -> (row = lane>>2, swizzled source col-block)
  const int srow = lane >> 2;
  const int scb  = ((lane & 3) - ((lane >> 3) & 3)) & 3;
  const int c0   = wave * 2;  // this wave stages 16-row chunks c0, c0+1 of A and B

  const __hip_bfloat16* gA = A + (size_t)(m0 + c0 * 16 + srow) * K + scb * 8;
  const __hip_bfloat16* gB = Bt + (size_t)(n0 + c0 * 16 + srow) * K + scb * 8;

  f32x4 acc[4][4] = {};

  const int rsel = lane & 15;
  const int cls  = ((lane >> 4) + ((lane >> 1) & 3)) & 3;  // read-side swizzle class

  auto stage = [&](int kt, int buf) {
    char* la = (char*)lds + buf * 16384 + c0 * 1024;
    const __hip_bfloat16* a = gA + kt * 32;
    async_copy16(la, a);
    async_copy16(la + 1024, a + 16 * K);
    char* lb = (char*)lds + buf * 16384 + 8192 + c0 * 1024;
    const __hip_bfloat16* b = gB + kt * 32;
    async_copy16(lb, b);
    async_copy16(lb + 1024, b + 16 * K);
  };

  stage(0, 0);
  stage(1, 1);

#pragma unroll
  for (int kt = 0; kt < NT; ++kt) {
    // Outstanding here: tiles kt, kt+1 (8 loads).  Drain to tile kt landed.
    if (kt < NT - 1) { VM_WAIT(4); } else { VM_WAIT(0); }
    __builtin_amdgcn_s_barrier();

    const __hip_bfloat16* base = lds + (kt % 3) * 8192;
    bf16x8 af[4], bg[4];
#pragma unroll
    for (int i = 0; i < 4; ++i) {
      af[i] = *reinterpret_cast<const bf16x8*>(
          base + (wm * 64 + i * 16 + rsel) * 32 + cls * 8);
      bg[i] = *reinterpret_cast<const bf16x8*>(
          base + 4096 + (wn * 64 + i * 16 + rsel) * 32 + cls * 8);
    }
    LGKM_WAIT0;                          // frags in regs
    __builtin_amdgcn_sched_barrier(0);   // rule 18
    __builtin_amdgcn_s_barrier();        // all waves done reading buf kt%3

    if (kt + 2 < NT) stage(kt + 2, (kt + 2) % 3);

    __builtin_amdgcn_s_setprio(1);
#pragma unroll
    for (int i = 0; i < 4; ++i)
#pragma unroll
      for (int j = 0; j < 4; ++j)
        acc[i][j] = __builtin_amdgcn_mfma_f32_16x16x32_bf16(af[i], bg[j],
                                                            acc[i][j], 0, 0, 0);
    __builtin_amdgcn_s_setprio(0);
  }

  // Epilogue.  C/D layout: col = lane&15, row = (lane>>4)*4 + e  [verified m89]
  const int rbase = m0 + wm * 64 + (lane >> 4) * 4;
  const int cbase = n0 + wn * 64 + (lane & 15);
#pragma unroll
  for (int i = 0; i < 4; ++i) {
#pragma unroll
    for (int j = 0; j < 4; ++j) {
#pragma unroll
      for (int e = 0; e < 4; ++e) {
        const int row = rbase + i * 16 + e;
        const int col = cbase + j * 16;
        float v = acc[i][j][e];
        if (MODE == 0) {
          v += bias[col];
          if (col >= 256) v = sigmoid_f(v);
          ((__hip_bfloat16*)out)[(size_t)row * 768 + col] = __float2bfloat16(v);
        } else if (MODE == 1) {
          if (col < 51) {
            v += bias[col];
            ((float*)out)[(size_t)row * 51 + col] = v;
          }
        } else {
          v += bias[col];
          ((__hip_bfloat16*)out)[(size_t)row * 256 + col] = __float2bfloat16(v);
        }
      }
    }
  }
}

// -------------------------------------------------------------------------
// Chunked linear-recurrence scan.  u[m][0:256]=x_tilde, [256:512]=f, [512:768]=r
// -------------------------------------------------------------------------
__global__ __launch_bounds__(256) void scan_p1(
    const __hip_bfloat16* __restrict__ u, float* __restrict__ Pa,
    float* __restrict__ Pb)
{
  const int blk = blockIdx.x;
  const int b = blk >> 5, ch = blk & 31;
  const int h = threadIdx.x;
  const __hip_bfloat16* base = u + (size_t)(b * 2048 + ch * TC) * 768;
  float c = 0.f, a = 1.f;
#pragma unroll 4
  for (int t = 0; t < TC; ++t) {
    float f  = __bfloat162float(base[t * 768 + 256 + h]);
    float xt = __bfloat162float(base[t * 768 + h]);
    c = f * c + (1.f - f) * xt;
    a *= f;
  }
  const int o = (b * NCHUNK + ch) * 256 + h;
  Pa[o] = a;
  Pb[o] = c;
}

__global__ __launch_bounds__(256) void scan_p2(
    const float* __restrict__ Pa, const float* __restrict__ Pb,
    float* __restrict__ Cin)
{
  const int idx = blockIdx.x * 256 + threadIdx.x;  // 8192 = 32 b * 256 h
  const int b = idx >> 8, h = idx & 255;
  float c = 0.f;
  for (int ch = 0; ch < NCHUNK; ++ch) {
    const int o = (b * NCHUNK + ch) * 256 + h;
    Cin[o] = c;
    c = Pa[o] * c + Pb[o];
  }
}

__global__ __launch_bounds__(256) void scan_p3(
    const __hip_bfloat16* __restrict__ u, const float* __restrict__ Cin,
    __hip_bfloat16* __restrict__ hout)
{
  const int blk = blockIdx.x;
  const int b = blk >> 5, ch = blk & 31;
  const int h = threadIdx.x;
  const __hip_bfloat16* base = u + (size_t)(b * 2048 + ch * TC) * 768;
  __hip_bfloat16* ob = hout + (size_t)(b * 2048 + ch * TC) * 256;
  float c = Cin[(b * NCHUNK + ch) * 256 + h];
#pragma unroll 2
  for (int t = 0; t < TC; ++t) {
    float xt = __bfloat162float(base[t * 768 + h]);
    float f  = __bfloat162float(base[t * 768 + 256 + h]);
    float r  = __bfloat162float(base[t * 768 + 512 + h]);
    c = f * c + (1.f - f) * xt;
    float th = tanh_f(c);
    ob[t * 256 + h] = __float2bfloat16(r * th + (1.f - r) * xt);
  }
}

// -------------------------------------------------------------------------
extern "C" void kernel_launch(void* const* d_in, const int* in_sizes, int n_in,
                              void* d_out, int out_size, void* d_ws, size_t ws_size,
                              hipStream_t stream) {
  const float* x     = (const float*)d_in[0];
  const float* W_in  = (const float*)d_in[1];
  const float* b_in  = (const float*)d_in[2];
  const float* W_l   = (const float*)d_in[3];
  const float* b_l   = (const float*)d_in[4];
  const float* W_out = (const float*)d_in[5];
  const float* b_out = (const float*)d_in[6];

  char* ws = (char*)d_ws;
  const size_t U_B    = (size_t)M_ROWS * 768 * 2;      // 100,663,296
  const size_t H_B    = (size_t)M_ROWS * 256 * 2;      //  33,554,432
  const size_t WT_B   = (size_t)2 * 768 * 256 * 2;     //     786,432
  const size_t WTO_B  = (size_t)128 * 256 * 2;         //      65,536
  const size_t WIN_B  = (size_t)256 * 64 * 2;          //      32,768
  const size_t XB_B   = (size_t)M_ROWS * 64 * 2;       //   8,388,608
  const size_t AB_B   = (size_t)32 * NCHUNK * 256 * 4; //   1,048,576

  size_t off = 0;
  __hip_bfloat16* u    = (__hip_bfloat16*)(ws + off); off += U_B;
  __hip_bfloat16* hA   = (__hip_bfloat16*)(ws + off); off += H_B;
  __hip_bfloat16* hB   = (__hip_bfloat16*)(ws + off); off += H_B;
  __hip_bfloat16* Wt   = (__hip_bfloat16*)(ws + off); off += WT_B;
  __hip_bfloat16* WtO  = (__hip_bfloat16*)(ws + off); off += WTO_B;
  __hip_bfloat16* WinT = (__hip_bfloat16*)(ws + off); off += WIN_B;
  __hip_bfloat16* xb   = (__hip_bfloat16*)(ws + off); off += XB_B;
  float* Pa  = (float*)(ws + off); off += AB_B;
  float* Pb  = (float*)(ws + off); off += AB_B;
  float* Cin = (float*)(ws + off); off += AB_B;

  prep_weights<<<1728, 256, 0, stream>>>(W_l, W_out, W_in, Wt, WtO, WinT);
  cast_x<<<M_ROWS * 8 / 256, 256, 0, stream>>>(x, xb);

  // input GEMM: h0 = xb @ W_in^T + b_in   (K=64, NBN=2)
  gemm_mfma<64, 2><<<M_ROWS / 128 * 2, 256, 0, stream>>>(xb, WinT, b_in, hA);

  // layer 0
  gemm_mfma<256, 0><<<M_ROWS / 128 * 6, 256, 0, stream>>>(hA, Wt, b_l, u);
  scan_p1<<<32 * NCHUNK, 256, 0, stream>>>(u, Pa, Pb);
  scan_p2<<<32, 256, 0, stream>>>(Pa, Pb, Cin);
  scan_p3<<<32 * NCHUNK, 256, 0, stream>>>(u, Cin, hB);

  // layer 1
  gemm_mfma<256, 0><<<M_ROWS / 128 * 6, 256, 0, stream>>>(hB, Wt + 768 * 256,
                                                          b_l + 768, u);
  scan_p1<<<32 * NCHUNK, 256, 0, stream>>>(u, Pa, Pb);
  scan_p2<<<32, 256, 0, stream>>>(Pa, Pb, Cin);
  scan_p3<<<32 * NCHUNK, 256, 0, stream>>>(u, Cin, hA);

  // output GEMM
  gemm_mfma<256, 1><<<M_ROWS / 128, 256, 0, stream>>>(hA, WtO, b_out, d_out);

  (void)in_sizes; (void)n_in; (void)out_size; (void)ws_size;
}